// Round 13
// baseline (432.745 us; speedup 1.0000x reference)
//
#include <hip/hip_runtime.h>
#include <hip/hip_bf16.h>

// InstanSeg v12: v11 + candidate-chunked work items.
// v11 post-mortem: 1.5 items/wave -> stealing can't balance; one heavy
// (row,strip) item = ~100 candidates of serial chain owned by one wave
// (occupancy 11%, tail-dominated). Now: item = (row, strip, chunk of 32
// candidates), 23040 items = 7.5/wave; heavy strips processed by several
// waves concurrently. 5*32 = CAPW so chunk coverage == list coverage.

#define HH    384
#define WW    384
#define NE    32
#define NK    256
#define HALF  64
#define HWSZ  (HH * WW)
#define EPSV  1e-6f
#define CAPW  160     // per-wave (32px) candidate cap
#define CAPM  192     // per-block (64px) candidate cap
#define CHUNK 32
#define NCH   5       // NCH*CHUNK == CAPW
#define NITEMS (4608 * NCH)

typedef _Float16 half8 __attribute__((ext_vector_type(8)));
typedef _Float16 half2v __attribute__((ext_vector_type(2)));
typedef float floatx4 __attribute__((ext_vector_type(4)));

#define MFMA16(a, b, c) __builtin_amdgcn_mfma_f32_16x16x32_f16((a), (b), (c), 0, 0, 0)

__device__ __forceinline__ half2v pk_f16(float a, float b) {
    return __builtin_bit_cast(half2v, __builtin_amdgcn_cvt_pkrtz(a, b));
}

// center-out row order: heavy (central) rows dispatch first
__device__ __forceinline__ int row_order(int ri) {
    return (ri & 1) ? (191 - (ri >> 1)) : (192 + (ri >> 1));
}

// ---- ws layout (float-element offsets) ----
#define WS_DIST   0            // 4,194,304 f32 (16 MB)
#define WS_MSYM   4194304      // 65,536 f32
#define WS_W2F    4259840      // 16,384 f16 = 8,192 f32
#define WS_D      4268032      // 32,768 f16 = 16,384 f32
#define WS_CENTER 4284416      // 256 f32
#define WS_CTR    4284672      // 1 int (steal counter)
#define WS_G      4284928      // 18,874,368 f16 = 9,437,184 f32

// ---------------------------------------------------------------- prep ----
__global__ void prep_kernel(const float* __restrict__ M, const float* __restrict__ W1,
                            const float* __restrict__ W2, const float* __restrict__ c,
                            const float* __restrict__ b1,
                            float* __restrict__ Msym, _Float16* __restrict__ W2f,
                            _Float16* __restrict__ D, int* __restrict__ gctr) {
    int idx = blockIdx.x * 256 + threadIdx.x;
    if (idx == 0) *gctr = 0;
    {   // Msym
        int i = idx >> 8, j = idx & 255;
        Msym[idx] = (i == j) ? 1.0f : 0.5f * (M[i * NK + j] + M[j * NK + i]);
    }
    if (idx < 2048) {   // W2f B-frags: lane l elem j = W2[32s+8(l>>4)+j][16nt+(l&15)]
        int l = idx & 63;
        int col = ((idx >> 8) << 4) + (l & 15);
        int kb = ((idx >> 6) & 3) * 32 + 8 * (l >> 4);
        #pragma unroll
        for (int j = 0; j < 8; ++j)
            W2f[idx * 8 + j] = (_Float16)W2[(kb + j) * 128 + col];
    }
    if (idx < 32768) {  // D[k][h] = W1^T c_k - b1
        int k = idx >> 7, h = idx & 127;
        float s = -b1[h];
        #pragma unroll 8
        for (int e = 0; e < NE; ++e) s = fmaf(c[k * NE + e], W1[e * 128 + h], s);
        D[idx] = (_Float16)s;
    }
}

// --------------------------------------------------------------- gfeat ----
__global__ __launch_bounds__(256)
void gfeat_kernel(const float* __restrict__ x, const float* __restrict__ sigma,
                  const float* __restrict__ W1, _Float16* __restrict__ G) {
    int px = blockIdx.x * 256 + threadIdx.x;
    float f[34];
    #pragma unroll
    for (int e = 0; e < NE; ++e) f[e] = x[e * HWSZ + px];
    f[32] = sigma[px];
    f[33] = sigma[HWSZ + px];
    _Float16* gp = G + (size_t)px * 128;
    #pragma unroll 1
    for (int h0 = 0; h0 < 128; h0 += 8) {
        half8 hv;
        #pragma unroll
        for (int j = 0; j < 8; ++j) {
            float z = 0.0f;
            const float* w1 = W1 + (h0 + j);
            #pragma unroll
            for (int e = 0; e < 34; ++e) z = fmaf(f[e], w1[e * 128], z);
            hv[j] = (_Float16)z;
        }
        *(half8*)(gp + h0) = hv;
    }
}

// -------------------------------------------------------------- center2 ---
__global__ __launch_bounds__(128)
void center2_kernel(const _Float16* __restrict__ G, const _Float16* __restrict__ D,
                    const float* __restrict__ W2, const float* __restrict__ b2,
                    const float* __restrict__ W3, const float* __restrict__ b3,
                    const int* __restrict__ cent, float* __restrict__ center) {
    __shared__ float h1s[128];
    __shared__ float red[2];
    int k = blockIdx.x, j = threadIdx.x;
    int cy0 = cent[2 * k], cx0 = cent[2 * k + 1];
    const _Float16* g = G + ((size_t)cy0 * WW + cx0) * 128;
    h1s[j] = fmaxf((float)g[j] - (float)D[k * 128 + j], 0.0f);
    __syncthreads();
    float acc = 0.0f;
    #pragma unroll 8
    for (int i = 0; i < 128; ++i) acc = fmaf(h1s[i], W2[i * 128 + j], acc);
    float p = fmaxf(acc + b2[j], 0.0f) * W3[j];
    #pragma unroll
    for (int m = 1; m < 64; m <<= 1) p += __shfl_xor(p, m, 64);
    if ((j & 63) == 0) red[j >> 6] = p;
    __syncthreads();
    if (j == 0) center[k] = red[0] + red[1] + b3[0];
}

// ----------------------------------------------------------------- pix ----
// 768 persistent blocks x 256 thr; wave steals (row, strip, cand-chunk).
__global__ __launch_bounds__(256)
void pix_kernel(const _Float16* __restrict__ G, const _Float16* __restrict__ D,
                const _Float16* __restrict__ W2f, const int* __restrict__ cent,
                const float* __restrict__ b2, const float* __restrict__ W3,
                const float* __restrict__ b3, const float* __restrict__ center,
                int* __restrict__ gctr, float* __restrict__ dist) {
    __shared__ int   wl[4][CAPW];
    __shared__ float wc[4][CAPW];

    const int tid = threadIdx.x;
    const int l   = tid & 63;
    const int wv  = tid >> 6;
    const int lg  = l >> 4;
    const int xi  = l & 15;

    // ---- loop-invariant registers ----
    half8 B2w[8][4];
    const half8* W2f8 = (const half8*)W2f;
    #pragma unroll
    for (int n = 0; n < 8; ++n)
        #pragma unroll
        for (int s = 0; s < 4; ++s) B2w[n][s] = W2f8[(n * 4 + s) * 64 + l];

    float b2v[8][4];
    half2v w3pk[8][2];
    #pragma unroll
    for (int n = 0; n < 8; ++n) {
        #pragma unroll
        for (int q = 0; q < 4; ++q) b2v[n][q] = b2[16 * n + 4 * lg + q];
        #pragma unroll
        for (int q = 0; q < 2; ++q)
            w3pk[n][q] = half2v{(_Float16)W3[16 * n + 4 * lg + 2 * q],
                                (_Float16)W3[16 * n + 4 * lg + 2 * q + 1]};
    }
    const float b3s = b3[0];
    const half8 hz = half8{};
    const char* Dc = (const char*)D;
    const int2* c2 = (const int2*)cent;

    // ---- persistent steal loop ----
    #pragma unroll 1
    for (;;) {
        int pos = 0;
        if (l == 0) pos = atomicAdd(gctr, 1);
        pos = __shfl(pos, 0, 64);
        if (pos >= NITEMS) break;

        const int itm   = pos / NCH;
        const int chunk = pos - itm * NCH;
        const int r     = row_order(itm / 12);
        const int wx0   = (itm % 12) * 32;
        const int c0    = chunk * CHUNK;

        // per-wave exact candidate list (ballot-prefix, no barrier)
        int nw;
        {
            int base = 0;
            #pragma unroll
            for (int cch = 0; cch < 4; ++cch) {
                int j = cch * 64 + l;
                int2 cc = c2[j];
                int ty = min(max(cc.x, HALF), HH - HALF) - HALF;
                int tx = min(max(cc.y, HALF), WW - HALF) - HALF;
                bool f = (r >= ty) && (r < ty + 128) &&
                         (tx <= wx0 + 31) && (tx + 127 >= wx0);
                unsigned long long m = __ballot(f);
                int p2 = base + __popcll(m & ((1ull << l) - 1ull));
                if (f && p2 >= c0 && p2 < c0 + CHUNK && p2 < CAPW) {
                    wl[wv][p2] = (j << 20) | (ty << 10) | tx;
                    wc[wv][p2] = center[j];
                }
                base += __popcll(m);
            }
            nw = min(min(base, CAPW), c0 + CHUNK);
        }
        if (c0 >= nw) continue;

        // G fragments for this item's 32 px (two 16-px groups)
        half8 gA0[4], gA1[4];
        {
            const char* Gb0 = (const char*)G + ((size_t)r * WW + wx0 + xi) * 256 + lg * 16;
            const char* Gb1 = Gb0 + 16 * 256;
            #pragma unroll
            for (int s = 0; s < 4; ++s) {
                gA0[s] = *(const half8*)(Gb0 + s * 64);
                gA1[s] = *(const half8*)(Gb1 + s * 64);
            }
        }

        auto loadD = [&](half8* dst, int cp) {
            const char* Dp = Dc + (cp >> 20) * 256 + lg * 16;
            #pragma unroll
            for (int s = 0; s < 4; ++s) dst[s] = *(const half8*)(Dp + s * 64);
        };

        auto compute = [&](const half8* Dv, int cp, float bc) {
            half8 hin0[4], hin1[4];
            #pragma unroll
            for (int s = 0; s < 4; ++s) {
                hin0[s] = __builtin_elementwise_max(gA0[s] - Dv[s], hz);
                hin1[s] = __builtin_elementwise_max(gA1[s] - Dv[s], hz);
            }
            float p0 = 0.0f, p1 = 0.0f;
            #pragma unroll
            for (int n = 0; n < 8; ++n) {
                floatx4 a0 = floatx4{b2v[n][0], b2v[n][1], b2v[n][2], b2v[n][3]};
                floatx4 a1 = a0;
                #pragma unroll
                for (int s = 0; s < 4; ++s) {
                    a0 = MFMA16(B2w[n][s], hin0[s], a0);
                    a1 = MFMA16(B2w[n][s], hin1[s], a1);
                }
                half2v h00 = __builtin_elementwise_max(pk_f16(a0[0], a0[1]), half2v{});
                half2v h01 = __builtin_elementwise_max(pk_f16(a0[2], a0[3]), half2v{});
                half2v h10 = __builtin_elementwise_max(pk_f16(a1[0], a1[1]), half2v{});
                half2v h11 = __builtin_elementwise_max(pk_f16(a1[2], a1[3]), half2v{});
                p0 = __builtin_amdgcn_fdot2(h00, w3pk[n][0], p0, false);
                p0 = __builtin_amdgcn_fdot2(h01, w3pk[n][1], p0, false);
                p1 = __builtin_amdgcn_fdot2(h10, w3pk[n][0], p1, false);
                p1 = __builtin_amdgcn_fdot2(h11, w3pk[n][1], p1, false);
            }
            p0 += __shfl_xor(p0, 16, 64);
            p0 += __shfl_xor(p0, 32, 64);
            p1 += __shfl_xor(p1, 16, 64);
            p1 += __shfl_xor(p1, 32, 64);

            if (lg < 2) {
                float pv = (lg == 0) ? p0 : p1;
                int tx = cp & 1023, ty = (cp >> 10) & 1023, j = cp >> 20;
                int px = wx0 + lg * 16 + xi;
                unsigned dx = (unsigned)(px - tx);
                if (dx < 128u) {
                    float d = pv + b3s;
                    float mm = fmaxf(fmaxf(d, bc), 0.0f);
                    float lgv = mm + __logf(__expf(0.0f - mm) + __expf(d - mm) +
                                            __expf(bc - mm));
                    dist[((size_t)j << 14) + ((r - ty) << 7) + (int)dx] = d + bc - lgv;
                }
            }
        };

        // 2-stage software-pipelined candidate loop over [c0, nw)
        half8 Da[4], Db[4];
        int cpA = 0, cpB = 0;
        float bcA = 0.0f, bcB = 0.0f;
        cpA = wl[wv][c0]; bcA = wc[wv][c0]; loadD(Da, cpA);
        #pragma unroll 1
        for (int i = c0; i < nw; i += 2) {
            if (i + 1 < nw) { cpB = wl[wv][i + 1]; bcB = wc[wv][i + 1]; loadD(Db, cpB); }
            compute(Da, cpA, bcA);
            if (i + 1 >= nw) break;
            if (i + 2 < nw) { cpA = wl[wv][i + 2]; bcA = wc[wv][i + 2]; loadD(Da, cpA); }
            compute(Db, cpB, bcB);
        }
    }
}

// --------------------------------------------------------------- merge ----
// Grid = 384 rows x 6 xtiles = 2304 blocks of 256. dl staged as f16 (24KB).
__global__ __launch_bounds__(256)
void merge_kernel(const float* __restrict__ dist, const int* __restrict__ cent,
                  const float* __restrict__ Msym, float* __restrict__ out) {
    __shared__ _Float16 dl[CAPM][64];    // 24 KB
    __shared__ int   sjw[CAPM];
    __shared__ int2  mpk[4][CAPM];       // 6 KB {m bits, tx}
    __shared__ int   scnt;

    const int tid = threadIdx.x;
    const int l   = tid & 63;
    const int wv  = tid >> 6;
    const int r   = row_order(blockIdx.x / 6);
    const int xt  = blockIdx.x % 6;
    const int px  = xt * 64 + l;

    // ---- block candidate list (wave 0, ballot-prefix) ----
    if (wv == 0) {
        int base = 0;
        const int2* c2 = (const int2*)cent;
        #pragma unroll
        for (int cch = 0; cch < 4; ++cch) {
            int j = cch * 64 + l;
            int2 cc = c2[j];
            int ty = min(max(cc.x, HALF), HH - HALF) - HALF;
            int tx = min(max(cc.y, HALF), WW - HALF) - HALF;
            bool f = (r >= ty) && (r < ty + 128) &&
                     (tx <= xt * 64 + 63) && (tx + 127 >= xt * 64);
            unsigned long long m = __ballot(f);
            int pos = base + __popcll(m & ((1ull << l) - 1ull));
            if (f && pos < CAPM) sjw[pos] = (j << 20) | (ty << 10) | tx;
            base += __popcll(m);
        }
        if (l == 0) scnt = min(base, CAPM);
    }
    __syncthreads();
    const int nc = scnt;

    // ---- stage dl[j][px]: one coalesced dist row-segment per candidate ----
    #pragma unroll 1
    for (int j = wv; j < nc; j += 4) {
        int cp = sjw[j];
        int tx = cp & 1023, ty = (cp >> 10) & 1023, jj = cp >> 20;
        unsigned dx = (unsigned)(px - tx);
        float v = 0.0f;
        if (dx < 128u) v = dist[((size_t)jj << 14) + ((r - ty) << 7) + (int)dx];
        dl[j][l] = (_Float16)v;
    }
    __syncthreads();

    // ---- t-loop: one output window per wave-iteration ----
    #pragma unroll 1
    for (int t = wv; t < nc; t += 4) {
        int cpt = sjw[t];
        int kt = cpt >> 20;
        const float* mrow = Msym + kt * NK;
        #pragma unroll
        for (int cch = 0; cch < 3; ++cch) {      // compact (m, tx) pairs
            int j2 = cch * 64 + l;
            if (j2 < nc) {
                int cj = sjw[j2];
                mpk[wv][j2] = int2{__builtin_bit_cast(int, mrow[cj >> 20]),
                                   cj & 1023};
            }
        }
        float num = 0.0f, den = 0.0f;
        #pragma unroll 4
        for (int j = 0; j < nc; ++j) {
            int2 mp = mpk[wv][j];
            float m = __builtin_bit_cast(float, mp.x);
            num = fmaf(m, (float)dl[j][l], num); // dl = 0 where uncovered
            unsigned dxj = (unsigned)(px - mp.y);
            den += (dxj < 128u) ? m : 0.0f;
        }
        unsigned dxk = (unsigned)(px - (cpt & 1023));
        if (dxk < 128u)
            out[((size_t)kt << 14) + ((r - ((cpt >> 10) & 1023)) << 7) + (int)dxk] =
                num / fmaxf(den, EPSV);
    }
}

// -------------------------------------------------------------- launch ----
extern "C" void kernel_launch(void* const* d_in, const int* in_sizes, int n_in,
                              void* d_out, int out_size, void* d_ws, size_t ws_size,
                              hipStream_t stream) {
    const float* x     = (const float*)d_in[0];
    const float* sigma = (const float*)d_in[1];
    const float* c     = (const float*)d_in[2];
    const int*   cent  = (const int*)d_in[3];
    const float* M     = (const float*)d_in[4];
    const float* W1    = (const float*)d_in[5];
    const float* b1    = (const float*)d_in[6];
    const float* W2    = (const float*)d_in[7];
    const float* b2    = (const float*)d_in[8];
    const float* W3    = (const float*)d_in[9];
    const float* b3    = (const float*)d_in[10];
    float* out = (float*)d_out;

    float* ws       = (float*)d_ws;
    float* dist     = ws + WS_DIST;
    float* Msym     = ws + WS_MSYM;
    _Float16* W2f   = (_Float16*)(ws + WS_W2F);
    _Float16* D     = (_Float16*)(ws + WS_D);
    float* center   = ws + WS_CENTER;
    int*   gctr     = (int*)(ws + WS_CTR);
    _Float16* G     = (_Float16*)(ws + WS_G);

    prep_kernel<<<256, 256, 0, stream>>>(M, W1, W2, c, b1, Msym, W2f, D, gctr);
    gfeat_kernel<<<576, 256, 0, stream>>>(x, sigma, W1, G);
    center2_kernel<<<256, 128, 0, stream>>>(G, D, W2, b2, W3, b3, cent, center);
    pix_kernel<<<768, 256, 0, stream>>>(G, D, W2f, cent, b2, W3, b3, center,
                                        gctr, dist);
    merge_kernel<<<2304, 256, 0, stream>>>(dist, cent, Msym, out);
}

// Round 14
// 387.945 us; speedup vs baseline: 1.1155x; 1.1155x over previous
//
#include <hip/hip_runtime.h>
#include <hip/hip_bf16.h>

// InstanSeg v13: precomputed candidate lists + dense uniform-grain pix grid.
// v12 post-mortem: steal-atomic serialization + per-chunk ballot rebuild.
// Now: listbuild writes per-(row,strip) window lists ONCE to ws; pix is
// 46080 one-wave blocks (64 thr, no LDS/barriers/atomics), each = 16
// candidates of one strip, read straight from the list. Empty chunks exit
// after one load. Compute math identical to v11 (known-correct).

#define HH    384
#define WW    384
#define NE    32
#define NK    256
#define HALF  64
#define HWSZ  (HH * WW)
#define EPSV  1e-6f
#define CAP   160     // per-strip candidate cap
#define CHUNK 16
#define MAXCH 10      // MAXCH*CHUNK == CAP
#define NSTRIP (384 * 12)
#define CAPM  192     // merge per-block cap

typedef _Float16 half8 __attribute__((ext_vector_type(8)));
typedef _Float16 half2v __attribute__((ext_vector_type(2)));
typedef float floatx4 __attribute__((ext_vector_type(4)));

#define MFMA16(a, b, c) __builtin_amdgcn_mfma_f32_16x16x32_f16((a), (b), (c), 0, 0, 0)

__device__ __forceinline__ half2v pk_f16(float a, float b) {
    return __builtin_bit_cast(half2v, __builtin_amdgcn_cvt_pkrtz(a, b));
}

__device__ __forceinline__ int row_order(int ri) {
    return (ri & 1) ? (191 - (ri >> 1)) : (192 + (ri >> 1));
}

// ---- ws layout (float-element offsets) ----
#define WS_DIST   0            // 4,194,304 f32 (16 MB)
#define WS_MSYM   4194304      // 65,536 f32
#define WS_W2F    4259840      // 16,384 f16 = 8,192 f32
#define WS_D      4268032      // 32,768 f16 = 16,384 f32
#define WS_CENTER 4284416      // 256 f32
#define WS_LCNT   4284672      // 4,608 int
#define WS_LIST   4289280      // 737,280 int (4608 * 160)
#define WS_G      5026560      // 18,874,368 f16 = 9,437,184 f32

// ---------------------------------------------------------------- prep ----
__global__ void prep_kernel(const float* __restrict__ M, const float* __restrict__ W1,
                            const float* __restrict__ W2, const float* __restrict__ c,
                            const float* __restrict__ b1,
                            float* __restrict__ Msym, _Float16* __restrict__ W2f,
                            _Float16* __restrict__ D) {
    int idx = blockIdx.x * 256 + threadIdx.x;
    {   // Msym
        int i = idx >> 8, j = idx & 255;
        Msym[idx] = (i == j) ? 1.0f : 0.5f * (M[i * NK + j] + M[j * NK + i]);
    }
    if (idx < 2048) {   // W2f B-frags: lane l elem j = W2[32s+8(l>>4)+j][16nt+(l&15)]
        int l = idx & 63;
        int col = ((idx >> 8) << 4) + (l & 15);
        int kb = ((idx >> 6) & 3) * 32 + 8 * (l >> 4);
        #pragma unroll
        for (int j = 0; j < 8; ++j)
            W2f[idx * 8 + j] = (_Float16)W2[(kb + j) * 128 + col];
    }
    if (idx < 32768) {  // D[k][h] = W1^T c_k - b1
        int k = idx >> 7, h = idx & 127;
        float s = -b1[h];
        #pragma unroll 8
        for (int e = 0; e < NE; ++e) s = fmaf(c[k * NE + e], W1[e * 128 + h], s);
        D[idx] = (_Float16)s;
    }
}

// --------------------------------------------------------------- gfeat ----
__global__ __launch_bounds__(256)
void gfeat_kernel(const float* __restrict__ x, const float* __restrict__ sigma,
                  const float* __restrict__ W1, _Float16* __restrict__ G) {
    int px = blockIdx.x * 256 + threadIdx.x;
    float f[34];
    #pragma unroll
    for (int e = 0; e < NE; ++e) f[e] = x[e * HWSZ + px];
    f[32] = sigma[px];
    f[33] = sigma[HWSZ + px];
    _Float16* gp = G + (size_t)px * 128;
    #pragma unroll 1
    for (int h0 = 0; h0 < 128; h0 += 8) {
        half8 hv;
        #pragma unroll
        for (int j = 0; j < 8; ++j) {
            float z = 0.0f;
            const float* w1 = W1 + (h0 + j);
            #pragma unroll
            for (int e = 0; e < 34; ++e) z = fmaf(f[e], w1[e * 128], z);
            hv[j] = (_Float16)z;
        }
        *(half8*)(gp + h0) = hv;
    }
}

// -------------------------------------------------------------- center2 ---
__global__ __launch_bounds__(128)
void center2_kernel(const _Float16* __restrict__ G, const _Float16* __restrict__ D,
                    const float* __restrict__ W2, const float* __restrict__ b2,
                    const float* __restrict__ W3, const float* __restrict__ b3,
                    const int* __restrict__ cent, float* __restrict__ center) {
    __shared__ float h1s[128];
    __shared__ float red[2];
    int k = blockIdx.x, j = threadIdx.x;
    int cy0 = cent[2 * k], cx0 = cent[2 * k + 1];
    const _Float16* g = G + ((size_t)cy0 * WW + cx0) * 128;
    h1s[j] = fmaxf((float)g[j] - (float)D[k * 128 + j], 0.0f);
    __syncthreads();
    float acc = 0.0f;
    #pragma unroll 8
    for (int i = 0; i < 128; ++i) acc = fmaf(h1s[i], W2[i * 128 + j], acc);
    float p = fmaxf(acc + b2[j], 0.0f) * W3[j];
    #pragma unroll
    for (int m = 1; m < 64; m <<= 1) p += __shfl_xor(p, m, 64);
    if ((j & 63) == 0) red[j >> 6] = p;
    __syncthreads();
    if (j == 0) center[k] = red[0] + red[1] + b3[0];
}

// ----------------------------------------------------------- listbuild ----
// 1152 blocks x 256 thr; wave = strip item (row, 32px). Ballot-compacted
// window list -> glist[item*CAP + pos], count -> lcnt[item].
__global__ __launch_bounds__(256)
void listbuild_kernel(const int* __restrict__ cent, int* __restrict__ glist,
                      int* __restrict__ lcnt) {
    const int tid = threadIdx.x;
    const int l   = tid & 63;
    const int wv  = tid >> 6;
    const int item = blockIdx.x * 4 + wv;
    const int r    = item / 12;
    const int wx0  = (item % 12) * 32;

    int base = 0;
    const int2* c2 = (const int2*)cent;
    #pragma unroll
    for (int cch = 0; cch < 4; ++cch) {
        int j = cch * 64 + l;
        int2 cc = c2[j];
        int ty = min(max(cc.x, HALF), HH - HALF) - HALF;
        int tx = min(max(cc.y, HALF), WW - HALF) - HALF;
        bool f = (r >= ty) && (r < ty + 128) &&
                 (tx <= wx0 + 31) && (tx + 127 >= wx0);
        unsigned long long m = __ballot(f);
        int pos = base + __popcll(m & ((1ull << l) - 1ull));
        if (f && pos < CAP) glist[item * CAP + pos] = (j << 20) | (ty << 10) | tx;
        base += __popcll(m);
    }
    if (l == 0) lcnt[item] = min(base, CAP);
}

// ----------------------------------------------------------------- pix ----
// 46080 one-wave blocks (64 thr, no LDS): block = (strip item, chunk of 16).
__global__ __launch_bounds__(64)
void pix_kernel(const _Float16* __restrict__ G, const _Float16* __restrict__ D,
                const _Float16* __restrict__ W2f,
                const float* __restrict__ b2, const float* __restrict__ W3,
                const float* __restrict__ b3, const float* __restrict__ center,
                const int* __restrict__ glist, const int* __restrict__ lcnt,
                float* __restrict__ dist) {
    const int l  = threadIdx.x;
    const int lg = l >> 4;
    const int xi = l & 15;

    const int bid   = blockIdx.x;
    const int item  = bid / MAXCH;
    const int chunk = bid - item * MAXCH;
    const int c0    = chunk * CHUNK;

    const int nc = lcnt[item];
    const int ce = min(nc, c0 + CHUNK);
    if (c0 >= ce) return;

    const int r   = item / 12;
    const int wx0 = (item % 12) * 32;
    const int* lp = glist + item * CAP;

    // ---- loop-invariant registers ----
    half8 B2w[8][4];
    const half8* W2f8 = (const half8*)W2f;
    #pragma unroll
    for (int n = 0; n < 8; ++n)
        #pragma unroll
        for (int s = 0; s < 4; ++s) B2w[n][s] = W2f8[(n * 4 + s) * 64 + l];

    float b2v[8][4];
    half2v w3pk[8][2];
    #pragma unroll
    for (int n = 0; n < 8; ++n) {
        #pragma unroll
        for (int q = 0; q < 4; ++q) b2v[n][q] = b2[16 * n + 4 * lg + q];
        #pragma unroll
        for (int q = 0; q < 2; ++q)
            w3pk[n][q] = half2v{(_Float16)W3[16 * n + 4 * lg + 2 * q],
                                (_Float16)W3[16 * n + 4 * lg + 2 * q + 1]};
    }
    const float b3s = b3[0];
    const half8 hz = half8{};
    const char* Dc = (const char*)D;

    // G fragments for this strip's 32 px (two 16-px groups), loaded ONCE
    half8 gA0[4], gA1[4];
    {
        const char* Gb0 = (const char*)G + ((size_t)r * WW + wx0 + xi) * 256 + lg * 16;
        const char* Gb1 = Gb0 + 16 * 256;
        #pragma unroll
        for (int s = 0; s < 4; ++s) {
            gA0[s] = *(const half8*)(Gb0 + s * 64);
            gA1[s] = *(const half8*)(Gb1 + s * 64);
        }
    }

    auto loadD = [&](half8* dst, int cp) {
        const char* Dp = Dc + (cp >> 20) * 256 + lg * 16;
        #pragma unroll
        for (int s = 0; s < 4; ++s) dst[s] = *(const half8*)(Dp + s * 64);
    };

    auto compute = [&](const half8* Dv, int cp, float bc) {
        half8 hin0[4], hin1[4];
        #pragma unroll
        for (int s = 0; s < 4; ++s) {
            hin0[s] = __builtin_elementwise_max(gA0[s] - Dv[s], hz);
            hin1[s] = __builtin_elementwise_max(gA1[s] - Dv[s], hz);
        }
        float p0 = 0.0f, p1 = 0.0f;
        #pragma unroll
        for (int n = 0; n < 8; ++n) {
            floatx4 a0 = floatx4{b2v[n][0], b2v[n][1], b2v[n][2], b2v[n][3]};
            floatx4 a1 = a0;
            #pragma unroll
            for (int s = 0; s < 4; ++s) {
                a0 = MFMA16(B2w[n][s], hin0[s], a0);
                a1 = MFMA16(B2w[n][s], hin1[s], a1);
            }
            half2v h00 = __builtin_elementwise_max(pk_f16(a0[0], a0[1]), half2v{});
            half2v h01 = __builtin_elementwise_max(pk_f16(a0[2], a0[3]), half2v{});
            half2v h10 = __builtin_elementwise_max(pk_f16(a1[0], a1[1]), half2v{});
            half2v h11 = __builtin_elementwise_max(pk_f16(a1[2], a1[3]), half2v{});
            p0 = __builtin_amdgcn_fdot2(h00, w3pk[n][0], p0, false);
            p0 = __builtin_amdgcn_fdot2(h01, w3pk[n][1], p0, false);
            p1 = __builtin_amdgcn_fdot2(h10, w3pk[n][0], p1, false);
            p1 = __builtin_amdgcn_fdot2(h11, w3pk[n][1], p1, false);
        }
        p0 += __shfl_xor(p0, 16, 64);
        p0 += __shfl_xor(p0, 32, 64);
        p1 += __shfl_xor(p1, 16, 64);
        p1 += __shfl_xor(p1, 32, 64);

        if (lg < 2) {
            float pv = (lg == 0) ? p0 : p1;
            int tx = cp & 1023, ty = (cp >> 10) & 1023, j = cp >> 20;
            int px = wx0 + lg * 16 + xi;
            unsigned dx = (unsigned)(px - tx);
            if (dx < 128u) {
                float d = pv + b3s;
                float mm = fmaxf(fmaxf(d, bc), 0.0f);
                float lgv = mm + __logf(__expf(0.0f - mm) + __expf(d - mm) +
                                        __expf(bc - mm));
                dist[((size_t)j << 14) + ((r - ty) << 7) + (int)dx] = d + bc - lgv;
            }
        }
    };

    // ---- 2-stage software-pipelined candidate loop over [c0, ce) ----
    half8 Da[4], Db[4];
    int cpA, cpB = 0;
    float bcA, bcB = 0.0f;
    cpA = lp[c0]; bcA = center[cpA >> 20]; loadD(Da, cpA);
    #pragma unroll 1
    for (int i = c0; i < ce; i += 2) {
        if (i + 1 < ce) { cpB = lp[i + 1]; bcB = center[cpB >> 20]; loadD(Db, cpB); }
        compute(Da, cpA, bcA);
        if (i + 1 >= ce) break;
        if (i + 2 < ce) { cpA = lp[i + 2]; bcA = center[cpA >> 20]; loadD(Da, cpA); }
        compute(Db, cpB, bcB);
    }
}

// --------------------------------------------------------------- merge ----
__global__ __launch_bounds__(256)
void merge_kernel(const float* __restrict__ dist, const int* __restrict__ cent,
                  const float* __restrict__ Msym, float* __restrict__ out) {
    __shared__ _Float16 dl[CAPM][64];    // 24 KB
    __shared__ int   sjw[CAPM];
    __shared__ int2  mpk[4][CAPM];       // 6 KB {m bits, tx}
    __shared__ int   scnt;

    const int tid = threadIdx.x;
    const int l   = tid & 63;
    const int wv  = tid >> 6;
    const int r   = row_order(blockIdx.x / 6);
    const int xt  = blockIdx.x % 6;
    const int px  = xt * 64 + l;

    if (wv == 0) {
        int base = 0;
        const int2* c2 = (const int2*)cent;
        #pragma unroll
        for (int cch = 0; cch < 4; ++cch) {
            int j = cch * 64 + l;
            int2 cc = c2[j];
            int ty = min(max(cc.x, HALF), HH - HALF) - HALF;
            int tx = min(max(cc.y, HALF), WW - HALF) - HALF;
            bool f = (r >= ty) && (r < ty + 128) &&
                     (tx <= xt * 64 + 63) && (tx + 127 >= xt * 64);
            unsigned long long m = __ballot(f);
            int pos = base + __popcll(m & ((1ull << l) - 1ull));
            if (f && pos < CAPM) sjw[pos] = (j << 20) | (ty << 10) | tx;
            base += __popcll(m);
        }
        if (l == 0) scnt = min(base, CAPM);
    }
    __syncthreads();
    const int nc = scnt;

    #pragma unroll 1
    for (int j = wv; j < nc; j += 4) {
        int cp = sjw[j];
        int tx = cp & 1023, ty = (cp >> 10) & 1023, jj = cp >> 20;
        unsigned dx = (unsigned)(px - tx);
        float v = 0.0f;
        if (dx < 128u) v = dist[((size_t)jj << 14) + ((r - ty) << 7) + (int)dx];
        dl[j][l] = (_Float16)v;
    }
    __syncthreads();

    #pragma unroll 1
    for (int t = wv; t < nc; t += 4) {
        int cpt = sjw[t];
        int kt = cpt >> 20;
        const float* mrow = Msym + kt * NK;
        #pragma unroll
        for (int cch = 0; cch < 3; ++cch) {
            int j2 = cch * 64 + l;
            if (j2 < nc) {
                int cj = sjw[j2];
                mpk[wv][j2] = int2{__builtin_bit_cast(int, mrow[cj >> 20]),
                                   cj & 1023};
            }
        }
        float num = 0.0f, den = 0.0f;
        #pragma unroll 4
        for (int j = 0; j < nc; ++j) {
            int2 mp = mpk[wv][j];
            float m = __builtin_bit_cast(float, mp.x);
            num = fmaf(m, (float)dl[j][l], num);
            unsigned dxj = (unsigned)(px - mp.y);
            den += (dxj < 128u) ? m : 0.0f;
        }
        unsigned dxk = (unsigned)(px - (cpt & 1023));
        if (dxk < 128u)
            out[((size_t)kt << 14) + ((r - ((cpt >> 10) & 1023)) << 7) + (int)dxk] =
                num / fmaxf(den, EPSV);
    }
}

// -------------------------------------------------------------- launch ----
extern "C" void kernel_launch(void* const* d_in, const int* in_sizes, int n_in,
                              void* d_out, int out_size, void* d_ws, size_t ws_size,
                              hipStream_t stream) {
    const float* x     = (const float*)d_in[0];
    const float* sigma = (const float*)d_in[1];
    const float* c     = (const float*)d_in[2];
    const int*   cent  = (const int*)d_in[3];
    const float* M     = (const float*)d_in[4];
    const float* W1    = (const float*)d_in[5];
    const float* b1    = (const float*)d_in[6];
    const float* W2    = (const float*)d_in[7];
    const float* b2    = (const float*)d_in[8];
    const float* W3    = (const float*)d_in[9];
    const float* b3    = (const float*)d_in[10];
    float* out = (float*)d_out;

    float* ws       = (float*)d_ws;
    float* dist     = ws + WS_DIST;
    float* Msym     = ws + WS_MSYM;
    _Float16* W2f   = (_Float16*)(ws + WS_W2F);
    _Float16* D     = (_Float16*)(ws + WS_D);
    float* center   = ws + WS_CENTER;
    int*   lcnt     = (int*)(ws + WS_LCNT);
    int*   glist    = (int*)(ws + WS_LIST);
    _Float16* G     = (_Float16*)(ws + WS_G);

    prep_kernel<<<256, 256, 0, stream>>>(M, W1, W2, c, b1, Msym, W2f, D);
    gfeat_kernel<<<576, 256, 0, stream>>>(x, sigma, W1, G);
    center2_kernel<<<256, 128, 0, stream>>>(G, D, W2, b2, W3, b3, cent, center);
    listbuild_kernel<<<1152, 256, 0, stream>>>(cent, glist, lcnt);
    pix_kernel<<<NSTRIP * MAXCH, 64, 0, stream>>>(G, D, W2f, b2, W3, b3,
                                                  center, glist, lcnt, dist);
    merge_kernel<<<2304, 256, 0, stream>>>(dist, cent, Msym, out);
}